// Round 5
// baseline (1922.733 us; speedup 1.0000x reference)
//
#include <hip/hip_runtime.h>
#include <stdint.h>

typedef __bf16 bf16x8 __attribute__((ext_vector_type(8)));
typedef __bf16 bf16x4 __attribute__((ext_vector_type(4)));
typedef float f32x4v __attribute__((ext_vector_type(4)));

// ---------------------------------------------------------------------------
// QKV projection: C_f32[4096 x 4096] = hidden_f32 @ [qw|kw|vw]^T_f32.
// f32 global loads -> inline bf16 hi/lo split -> LDS -> 3-term split MFMA.
// grid (32, 32), block 256 (4 waves, 2x2 wave grid, 4x4 16x16x32 MFMA).
// ---------------------------------------------------------------------------
__global__ __launch_bounds__(256, 2) void gemm_qkv(
    const float* __restrict__ A, const float* __restrict__ B0,
    const float* __restrict__ B1, const float* __restrict__ B2,
    float* __restrict__ C) {
  const int K = 2048, ldc = 4096;
  __shared__ __align__(16) __bf16 Ash[128 * 32];
  __shared__ __align__(16) __bf16 Asl[128 * 32];
  __shared__ __align__(16) __bf16 Bsh[128 * 32];
  __shared__ __align__(16) __bf16 Bsl[128 * 32];
  const int m0 = blockIdx.y * 128, n0 = blockIdx.x * 128;
  const int tid = threadIdx.x;
  const int wid = tid >> 6, lane = tid & 63, l15 = lane & 15, quad = lane >> 4;
  const int wm = wid >> 1, wn = wid & 1;

  const float* Bp; int nb;
  if (n0 < 2048)      { Bp = B0; nb = n0; }
  else if (n0 < 3072) { Bp = B1; nb = n0 - 2048; }
  else                { Bp = B2; nb = n0 - 3072; }

  f32x4v acc[4][4] = {};

  for (int kb = 0; kb < K; kb += 32) {
    for (int cc = 0; cc < 4; ++cc) {
      const int c = cc * 256 + tid;        // lanes consecutive -> coalesced
      const int row = c >> 3, col = (c & 7) * 4;
      const float4 av = *(const float4*)(A + (size_t)(m0 + row) * K + kb + col);
      const float4 bv = *(const float4*)(Bp + (size_t)(nb + row) * K + kb + col);
      const float aa[4] = {av.x, av.y, av.z, av.w};
      const float bb[4] = {bv.x, bv.y, bv.z, bv.w};
      bf16x4 ah, al, bh, bl;
      for (int j = 0; j < 4; ++j) {
        ah[j] = (__bf16)aa[j]; al[j] = (__bf16)(aa[j] - (float)ah[j]);
        bh[j] = (__bf16)bb[j]; bl[j] = (__bf16)(bb[j] - (float)bh[j]);
      }
      *(bf16x4*)&Ash[row * 32 + col] = ah;
      *(bf16x4*)&Asl[row * 32 + col] = al;
      *(bf16x4*)&Bsh[row * 32 + col] = bh;
      *(bf16x4*)&Bsl[row * 32 + col] = bl;
    }
    __syncthreads();
    bf16x8 afh[4], afl[4], bfh[4], bfl[4];
    for (int mt = 0; mt < 4; ++mt) {
      const int o = (wm * 64 + mt * 16 + l15) * 32 + quad * 8;
      afh[mt] = *(const bf16x8*)&Ash[o];
      afl[mt] = *(const bf16x8*)&Asl[o];
    }
    for (int nt = 0; nt < 4; ++nt) {
      const int o = (wn * 64 + nt * 16 + l15) * 32 + quad * 8;
      bfh[nt] = *(const bf16x8*)&Bsh[o];
      bfl[nt] = *(const bf16x8*)&Bsl[o];
    }
    for (int mt = 0; mt < 4; ++mt)
      for (int nt = 0; nt < 4; ++nt) {
        acc[mt][nt] = __builtin_amdgcn_mfma_f32_16x16x32_bf16(afh[mt], bfh[nt], acc[mt][nt], 0, 0, 0);
        acc[mt][nt] = __builtin_amdgcn_mfma_f32_16x16x32_bf16(afh[mt], bfl[nt], acc[mt][nt], 0, 0, 0);
        acc[mt][nt] = __builtin_amdgcn_mfma_f32_16x16x32_bf16(afl[mt], bfh[nt], acc[mt][nt], 0, 0, 0);
      }
    __syncthreads();
  }
  // C/D layout: col = lane&15, row = quad*4 + reg
  for (int mt = 0; mt < 4; ++mt)
    for (int nt = 0; nt < 4; ++nt) {
      const int row = m0 + wm * 64 + mt * 16 + quad * 4;
      const int col = n0 + wn * 64 + nt * 16 + l15;
      for (int r = 0; r < 4; ++r)
        C[(size_t)(row + r) * ldc + col] = acc[mt][nt][r];
    }
}

// ---------------------------------------------------------------------------
// RMSNorm + RoPE, all f32. grid (4096, 16), block 64 (one wave).
// chunk 0..7 -> q head, 8..11 -> k head, 12..15 -> v head (norm only).
// Outputs: qf32 [8][S][256] f32, kf32 [4][S][256] f32, vN [4][S][256] bf16.
// ---------------------------------------------------------------------------
__global__ __launch_bounds__(64) void norm_rope(
    const float* __restrict__ qkv, const float* __restrict__ cosb,
    const float* __restrict__ sinb, const float* __restrict__ qnw,
    const float* __restrict__ knw, float* __restrict__ qo,
    float* __restrict__ ko, __bf16* __restrict__ vN) {
  const int s = blockIdx.x, c = blockIdx.y, lane = threadIdx.x;
  const int d0 = lane * 4;
  const float4 xv = *(const float4*)(qkv + (size_t)s * 4096 + c * 256 + d0);
  float v[4] = {xv.x, xv.y, xv.z, xv.w};
  float ss = v[0] * v[0] + v[1] * v[1] + v[2] * v[2] + v[3] * v[3];
  for (int off = 1; off < 64; off <<= 1) ss += __shfl_xor(ss, off);
  const float rn = rsqrtf(ss * (1.0f / 256.0f) + 1e-6f);
  if (c < 12) {
    const float* w = (c < 8) ? qnw : knw;
    float y[4], yp[4];
    for (int j = 0; j < 4; ++j) y[j] = v[j] * rn * w[d0 + j];
    for (int j = 0; j < 4; ++j) yp[j] = __shfl_xor(y[j], 32);  // d partner +/-128
    for (int j = 0; j < 4; ++j) {
      const int d = d0 + j;
      const float rot = (d < 128) ? -yp[j] : yp[j];
      y[j] = y[j] * cosb[s * 256 + d] + rot * sinb[s * 256 + d];
    }
    float* dst = (c < 8) ? (qo + ((size_t)c * 4096 + s) * 256)
                         : (ko + ((size_t)(c - 8) * 4096 + s) * 256);
    *(float4*)(dst + d0) = make_float4(y[0], y[1], y[2], y[3]);
  } else {
    bf16x4 o;
    for (int j = 0; j < 4; ++j) o[j] = (__bf16)(v[j] * rn);
    *(bf16x4*)(vN + ((size_t)(c - 12) * 4096 + s) * 256 + d0) = o;
  }
}

// ---------------------------------------------------------------------------
// Simple f32 VALU attention (validated path). Sliding window 1024, causal,
// NO softmax scale. grid (512, 8): block = (head h, 8 queries), 256 threads.
// GQA: kv head = h>>1. Writes attn [S][2048] bf16.
// ---------------------------------------------------------------------------
__global__ __launch_bounds__(256) void attn_simple(
    const float* __restrict__ Qf, const float* __restrict__ Kf,
    const __bf16* __restrict__ Vn, __bf16* __restrict__ Aout) {
  const int h = blockIdx.y, i0 = blockIdx.x * 8, kv = h >> 1, t = threadIdx.x;
  __shared__ float qs[8][256];       // 8 KB
  __shared__ float sc[8][1032];      // 33 KB (span <= 1031)
  __shared__ float wred[4];
  __shared__ float linvs[8];
  const int jlo = (i0 >= 1023) ? (i0 - 1023) : 0;
  const int jhi = i0 + 7;
  const int span = jhi - jlo + 1;

  const float* Qh = Qf + ((size_t)h * 4096 + i0) * 256;
  for (int u = t; u < 2048; u += 256) qs[u >> 8][u & 255] = Qh[u];
  __syncthreads();

  // scores: thread t handles keys j = jlo + t + 256u
  const float* Kh = Kf + (size_t)kv * 4096 * 256;
  float a[5][8] = {};
  for (int dq = 0; dq < 64; ++dq) {
    float4 qreg[8];
    for (int q = 0; q < 8; ++q) qreg[q] = *(const float4*)&qs[q][dq * 4];
    for (int u = 0; u < 5; ++u) {
      const int j = jlo + t + (u << 8);
      if (j <= jhi) {
        const float4 k4 = *(const float4*)(Kh + (size_t)j * 256 + dq * 4);
        for (int q = 0; q < 8; ++q)
          a[u][q] += qreg[q].x * k4.x + qreg[q].y * k4.y + qreg[q].z * k4.z + qreg[q].w * k4.w;
      }
    }
  }
  for (int u = 0; u < 5; ++u) {
    const int uu = t + (u << 8);
    if (uu < span)
      for (int q = 0; q < 8; ++q) sc[q][uu] = a[u][q];
  }
  __syncthreads();

  // masked softmax per query row
  for (int q = 0; q < 8; ++q) {
    const int i = i0 + q;
    float m = -1e30f;
    for (int u = t; u < span; u += 256) {
      const int j = jlo + u;
      const float s = ((j <= i) && (i - j < 1024)) ? sc[q][u] : -1e30f;
      m = fmaxf(m, s);
    }
    for (int off = 1; off < 64; off <<= 1) m = fmaxf(m, __shfl_xor(m, off));
    if ((t & 63) == 0) wred[t >> 6] = m;
    __syncthreads();
    m = fmaxf(fmaxf(wred[0], wred[1]), fmaxf(wred[2], wred[3]));
    __syncthreads();
    float ps = 0.f;
    for (int u = t; u < span; u += 256) {
      const int j = jlo + u;
      const float p = ((j <= i) && (i - j < 1024)) ? __expf(sc[q][u] - m) : 0.f;
      sc[q][u] = p;
      ps += p;
    }
    for (int off = 1; off < 64; off <<= 1) ps += __shfl_xor(ps, off);
    if ((t & 63) == 0) wred[t >> 6] = ps;
    __syncthreads();
    if (t == 0) linvs[q] = 1.f / (wred[0] + wred[1] + wred[2] + wred[3]);
    __syncthreads();
  }

  // PV: thread owns (q = t>>5, dims d = (t&31)*8 .. +7)
  const int qq = t >> 5, d8 = (t & 31) << 3;
  const __bf16* Vh = Vn + (size_t)kv * 4096 * 256;
  float acc[8] = {};
  for (int u = 0; u < span; ++u) {
    const float p = sc[qq][u];
    const bf16x8 v8 = *(const bf16x8*)(Vh + (size_t)(jlo + u) * 256 + d8);
    for (int e = 0; e < 8; ++e) acc[e] += p * (float)v8[e];
  }
  const float li = linvs[qq];
  __bf16* dst = Aout + (size_t)(i0 + qq) * 2048 + h * 256 + d8;
  for (int e = 0; e < 8; ++e) dst[e] = (__bf16)(acc[e] * li);
}

// ---------------------------------------------------------------------------
// O projection: out_f32[4096 x 2048] = attn_bf16 @ ow_f32^T (ow cast inline).
// *** OUTPUT IS f32 (reference output dtype) — the round-4 fix. ***
// grid (16, 32), block 256.
// ---------------------------------------------------------------------------
__global__ __launch_bounds__(256, 2) void gemm_out(
    const __bf16* __restrict__ A, const float* __restrict__ B,
    float* __restrict__ C) {
  const int K = 2048, ldc = 2048;
  __shared__ __align__(16) __bf16 As[128 * 32];
  __shared__ __align__(16) __bf16 Bs[128 * 32];
  const int m0 = blockIdx.y * 128, n0 = blockIdx.x * 128;
  const int tid = threadIdx.x;
  const int wid = tid >> 6, lane = tid & 63, l15 = lane & 15, quad = lane >> 4;
  const int wm = wid >> 1, wn = wid & 1;

  f32x4v acc[4][4] = {};

  for (int kb = 0; kb < K; kb += 32) {
    for (int cc = 0; cc < 2; ++cc) {            // A: 512 bf16x8 chunks
      const int c = cc * 256 + tid;
      const int row = c >> 2, col = (c & 3) * 8;
      *(bf16x8*)&As[row * 32 + col] =
          *(const bf16x8*)(A + (size_t)(m0 + row) * K + kb + col);
    }
    for (int cc = 0; cc < 4; ++cc) {            // B: 1024 float4 chunks -> bf16
      const int c = cc * 256 + tid;
      const int row = c >> 3, col = (c & 7) * 4;
      const float4 bv = *(const float4*)(B + (size_t)(n0 + row) * K + kb + col);
      bf16x4 bh = {(__bf16)bv.x, (__bf16)bv.y, (__bf16)bv.z, (__bf16)bv.w};
      *(bf16x4*)&Bs[row * 32 + col] = bh;
    }
    __syncthreads();
    bf16x8 af[4], bfr[4];
    for (int mt = 0; mt < 4; ++mt)
      af[mt] = *(const bf16x8*)&As[(wm * 64 + mt * 16 + l15) * 32 + quad * 8];
    for (int nt = 0; nt < 4; ++nt)
      bfr[nt] = *(const bf16x8*)&Bs[(wn * 64 + nt * 16 + l15) * 32 + quad * 8];
    for (int mt = 0; mt < 4; ++mt)
      for (int nt = 0; nt < 4; ++nt)
        acc[mt][nt] = __builtin_amdgcn_mfma_f32_16x16x32_bf16(af[mt], bfr[nt], acc[mt][nt], 0, 0, 0);
    __syncthreads();
  }
  for (int mt = 0; mt < 4; ++mt)
    for (int nt = 0; nt < 4; ++nt) {
      const int row = m0 + wm * 64 + mt * 16 + quad * 4;
      const int col = n0 + wn * 64 + nt * 16 + l15;
      for (int r = 0; r < 4; ++r)
        C[(size_t)(row + r) * ldc + col] = acc[mt][nt][r];
    }
}

// ---------------------------------------------------------------------------
extern "C" void kernel_launch(void* const* d_in, const int* in_sizes, int n_in,
                              void* d_out, int out_size, void* d_ws, size_t ws_size,
                              hipStream_t stream) {
  const float* hidden = (const float*)d_in[0];
  const float* cosb   = (const float*)d_in[1];
  const float* sinb   = (const float*)d_in[2];
  const float* qw     = (const float*)d_in[3];
  const float* kw     = (const float*)d_in[4];
  const float* vw     = (const float*)d_in[5];
  const float* ow     = (const float*)d_in[6];
  const float* qnw    = (const float*)d_in[7];
  const float* knw    = (const float*)d_in[8];
  float* out = (float*)d_out;   // reference output dtype = float32

  // Workspace (120 MiB peak), lifetime-overlapped:
  //  [0,64)Mi   qkvf (f32)  -> dead after norm_rope -> attn bf16 [0,16)
  //  [64,96)Mi  qf32        [96,112)Mi kf32        [112,120)Mi vN (bf16)
  const size_t MB = 1048576;
  char* ws = (char*)d_ws;
  float*  qkvf = (float*)ws;
  __bf16* attn = (__bf16*)ws;
  float*  qf   = (float*)(ws + 64 * MB);
  float*  kf   = (float*)(ws + 96 * MB);
  __bf16* vN   = (__bf16*)(ws + 112 * MB);

  // 1) QKV projection (split-precision MFMA, f32 out)
  gemm_qkv<<<dim3(32, 32), 256, 0, stream>>>(hidden, qw, kw, vw, qkvf);
  // 2) f32 RMSNorm + RoPE
  norm_rope<<<dim3(4096, 16), 64, 0, stream>>>(qkvf, cosb, sinb, qnw, knw, qf, kf, vN);
  // 3) simple f32 sliding-window attention
  attn_simple<<<dim3(512, 8), 256, 0, stream>>>(qf, kf, vN, attn);
  // 4) O projection -> f32 output
  gemm_out<<<dim3(16, 32), 256, 0, stream>>>(attn, ow, out);
}

// Round 6
// 1067.546 us; speedup vs baseline: 1.8011x; 1.8011x over previous
//
#include <hip/hip_runtime.h>
#include <stdint.h>

typedef __bf16 bf16x8 __attribute__((ext_vector_type(8)));
typedef __bf16 bf16x4 __attribute__((ext_vector_type(4)));
typedef float f32x4v __attribute__((ext_vector_type(4)));

// ---------------------------------------------------------------------------
// QKV projection: C_f32[4096 x 4096] = hidden_f32 @ [qw|kw|vw]^T_f32.
// f32 global loads -> inline bf16 hi/lo split -> LDS -> 3-term split MFMA.
// grid (32, 32), block 256 (4 waves, 2x2 wave grid, 4x4 16x16x32 MFMA).
// [validated round 5]
// ---------------------------------------------------------------------------
__global__ __launch_bounds__(256, 2) void gemm_qkv(
    const float* __restrict__ A, const float* __restrict__ B0,
    const float* __restrict__ B1, const float* __restrict__ B2,
    float* __restrict__ C) {
  const int K = 2048, ldc = 4096;
  __shared__ __align__(16) __bf16 Ash[128 * 32];
  __shared__ __align__(16) __bf16 Asl[128 * 32];
  __shared__ __align__(16) __bf16 Bsh[128 * 32];
  __shared__ __align__(16) __bf16 Bsl[128 * 32];
  const int m0 = blockIdx.y * 128, n0 = blockIdx.x * 128;
  const int tid = threadIdx.x;
  const int wid = tid >> 6, lane = tid & 63, l15 = lane & 15, quad = lane >> 4;
  const int wm = wid >> 1, wn = wid & 1;

  const float* Bp; int nb;
  if (n0 < 2048)      { Bp = B0; nb = n0; }
  else if (n0 < 3072) { Bp = B1; nb = n0 - 2048; }
  else                { Bp = B2; nb = n0 - 3072; }

  f32x4v acc[4][4] = {};

  for (int kb = 0; kb < K; kb += 32) {
    for (int cc = 0; cc < 4; ++cc) {
      const int c = cc * 256 + tid;        // lanes consecutive -> coalesced
      const int row = c >> 3, col = (c & 7) * 4;
      const float4 av = *(const float4*)(A + (size_t)(m0 + row) * K + kb + col);
      const float4 bv = *(const float4*)(Bp + (size_t)(nb + row) * K + kb + col);
      const float aa[4] = {av.x, av.y, av.z, av.w};
      const float bb[4] = {bv.x, bv.y, bv.z, bv.w};
      bf16x4 ah, al, bh, bl;
      for (int j = 0; j < 4; ++j) {
        ah[j] = (__bf16)aa[j]; al[j] = (__bf16)(aa[j] - (float)ah[j]);
        bh[j] = (__bf16)bb[j]; bl[j] = (__bf16)(bb[j] - (float)bh[j]);
      }
      *(bf16x4*)&Ash[row * 32 + col] = ah;
      *(bf16x4*)&Asl[row * 32 + col] = al;
      *(bf16x4*)&Bsh[row * 32 + col] = bh;
      *(bf16x4*)&Bsl[row * 32 + col] = bl;
    }
    __syncthreads();
    bf16x8 afh[4], afl[4], bfh[4], bfl[4];
    for (int mt = 0; mt < 4; ++mt) {
      const int o = (wm * 64 + mt * 16 + l15) * 32 + quad * 8;
      afh[mt] = *(const bf16x8*)&Ash[o];
      afl[mt] = *(const bf16x8*)&Asl[o];
    }
    for (int nt = 0; nt < 4; ++nt) {
      const int o = (wn * 64 + nt * 16 + l15) * 32 + quad * 8;
      bfh[nt] = *(const bf16x8*)&Bsh[o];
      bfl[nt] = *(const bf16x8*)&Bsl[o];
    }
    for (int mt = 0; mt < 4; ++mt)
      for (int nt = 0; nt < 4; ++nt) {
        acc[mt][nt] = __builtin_amdgcn_mfma_f32_16x16x32_bf16(afh[mt], bfh[nt], acc[mt][nt], 0, 0, 0);
        acc[mt][nt] = __builtin_amdgcn_mfma_f32_16x16x32_bf16(afh[mt], bfl[nt], acc[mt][nt], 0, 0, 0);
        acc[mt][nt] = __builtin_amdgcn_mfma_f32_16x16x32_bf16(afl[mt], bfh[nt], acc[mt][nt], 0, 0, 0);
      }
    __syncthreads();
  }
  // C/D layout: col = lane&15, row = quad*4 + reg
  for (int mt = 0; mt < 4; ++mt)
    for (int nt = 0; nt < 4; ++nt) {
      const int row = m0 + wm * 64 + mt * 16 + quad * 4;
      const int col = n0 + wn * 64 + nt * 16 + l15;
      for (int r = 0; r < 4; ++r)
        C[(size_t)(row + r) * ldc + col] = acc[mt][nt][r];
    }
}

// ---------------------------------------------------------------------------
// RMSNorm + RoPE, f32 internal. grid (4096, 16), block 64 (one wave).
// chunk 0..7 -> q head (hi/lo planes), 8..11 -> k head (hi/lo planes),
// 12..15 -> v head (norm only, bf16, TRANSPOSED [kvh][256][S] for PV).
// ---------------------------------------------------------------------------
__global__ __launch_bounds__(64) void norm_rope(
    const float* __restrict__ qkv, const float* __restrict__ cosb,
    const float* __restrict__ sinb, const float* __restrict__ qnw,
    const float* __restrict__ knw,
    __bf16* __restrict__ qh, __bf16* __restrict__ ql,
    __bf16* __restrict__ kh, __bf16* __restrict__ kl,
    __bf16* __restrict__ vT) {
  const int s = blockIdx.x, c = blockIdx.y, lane = threadIdx.x;
  const int d0 = lane * 4;
  const float4 xv = *(const float4*)(qkv + (size_t)s * 4096 + c * 256 + d0);
  float v[4] = {xv.x, xv.y, xv.z, xv.w};
  float ss = v[0] * v[0] + v[1] * v[1] + v[2] * v[2] + v[3] * v[3];
  for (int off = 1; off < 64; off <<= 1) ss += __shfl_xor(ss, off);
  const float rn = rsqrtf(ss * (1.0f / 256.0f) + 1e-6f);
  if (c < 12) {
    const float* w = (c < 8) ? qnw : knw;
    float y[4], yp[4];
    for (int j = 0; j < 4; ++j) y[j] = v[j] * rn * w[d0 + j];
    for (int j = 0; j < 4; ++j) yp[j] = __shfl_xor(y[j], 32);  // d partner +/-128
    for (int j = 0; j < 4; ++j) {
      const int d = d0 + j;
      const float rot = (d < 128) ? -yp[j] : yp[j];
      y[j] = y[j] * cosb[s * 256 + d] + rot * sinb[s * 256 + d];
    }
    const size_t o = (c < 8) ? ((size_t)c * 4096 + s) * 256 + d0
                             : ((size_t)(c - 8) * 4096 + s) * 256 + d0;
    __bf16* dh = (c < 8) ? qh : kh;
    __bf16* dl = (c < 8) ? ql : kl;
    bf16x4 hv, lv;
    for (int j = 0; j < 4; ++j) {
      hv[j] = (__bf16)y[j];
      lv[j] = (__bf16)(y[j] - (float)hv[j]);
    }
    *(bf16x4*)(dh + o) = hv;
    *(bf16x4*)(dl + o) = lv;
  } else {
    const int kvh = c - 12;
    for (int j = 0; j < 4; ++j)
      vT[(size_t)(kvh * 256 + d0 + j) * 4096 + s] = (__bf16)(v[j] * rn);
  }
}

// ---------------------------------------------------------------------------
// MFMA flash attention, sliding window 1024, causal, NO softmax scale.
// QK^T split-precision (hi*hi + hi*lo + lo*hi, score err ~3e-4); PV bf16.
// grid (S/64, H=8), block 256 (4 waves; wave w owns queries q0+16w..+15).
// GQA kv head = h>>1. Writes attn [S][2048] bf16.
// ---------------------------------------------------------------------------
__global__ __launch_bounds__(256, 2) void attn_mfma(
    const __bf16* __restrict__ Qh_, const __bf16* __restrict__ Ql_,
    const __bf16* __restrict__ Kh_, const __bf16* __restrict__ Kl_,
    const __bf16* __restrict__ VT, __bf16* __restrict__ Aout) {
  const int S = 4096, D = 256;
  const int h = blockIdx.y;
  const int q0 = blockIdx.x * 64;
  const int tid = threadIdx.x;
  const int wid = tid >> 6, lane = tid & 63, l15 = lane & 15, quad = lane >> 4;
  const int kv = h >> 1;
  __shared__ __align__(16) __bf16 P[4][16][64];  // per-wave P C->A round-trip

  const __bf16* Khh = Kh_ + (size_t)kv * S * D;
  const __bf16* Khl = Kl_ + (size_t)kv * S * D;
  const __bf16* Vh  = VT + (size_t)kv * D * S;

  // Q fragments hi/lo (A-layout: m=lane&15, k=quad*8+j)
  bf16x8 qfh[8], qfl[8];
  {
    const size_t qoff = (size_t)h * S * D + (size_t)(q0 + wid * 16 + l15) * D + quad * 8;
    for (int ks = 0; ks < 8; ++ks) {
      qfh[ks] = *(const bf16x8*)(Qh_ + qoff + ks * 32);
      qfl[ks] = *(const bf16x8*)(Ql_ + qoff + ks * 32);
    }
  }

  f32x4v O[16] = {};
  float mrow[4] = {-1e30f, -1e30f, -1e30f, -1e30f};
  float lrow[4] = {0.f, 0.f, 0.f, 0.f};

  const int lo = (q0 >= 1024) ? (q0 - 1024) : 0;
  for (int kt = lo; kt <= q0; kt += 64) {
    // scores [16 q x 64 keys]: 4 n-tiles x 8 k-steps x 3 split terms
    f32x4v sa[4] = {};
    for (int nt = 0; nt < 4; ++nt) {
      const size_t ko = (size_t)(kt + nt * 16 + l15) * D + quad * 8;
      for (int ks = 0; ks < 8; ++ks) {
        const bf16x8 kh8 = *(const bf16x8*)(Khh + ko + ks * 32);
        const bf16x8 kl8 = *(const bf16x8*)(Khl + ko + ks * 32);
        sa[nt] = __builtin_amdgcn_mfma_f32_16x16x32_bf16(qfh[ks], kh8, sa[nt], 0, 0, 0);
        sa[nt] = __builtin_amdgcn_mfma_f32_16x16x32_bf16(qfh[ks], kl8, sa[nt], 0, 0, 0);
        sa[nt] = __builtin_amdgcn_mfma_f32_16x16x32_bf16(qfl[ks], kh8, sa[nt], 0, 0, 0);
      }
    }
    // online softmax (C-layout: row = quad*4+r, col = l15 within n-tile)
    float al[4];
    for (int r = 0; r < 4; ++r) {
      const int i = q0 + wid * 16 + quad * 4 + r;
      float mx = -1e30f;
      for (int nt = 0; nt < 4; ++nt) {
        const int j = kt + nt * 16 + l15;
        const float svv = ((j <= i) && (i - j < 1024)) ? sa[nt][r] : -1e30f;
        sa[nt][r] = svv;
        mx = fmaxf(mx, svv);
      }
      for (int off = 1; off < 16; off <<= 1) mx = fmaxf(mx, __shfl_xor(mx, off));
      const float mn = fmaxf(mrow[r], mx);
      al[r] = __expf(mrow[r] - mn);
      float ps = 0.f;
      for (int nt = 0; nt < 4; ++nt) {
        // explicit zero for fully-masked history (else exp(0)=1 garbage)
        const float p = (mn <= -1e29f) ? 0.f : __expf(sa[nt][r] - mn);
        P[wid][quad * 4 + r][nt * 16 + l15] = (__bf16)p;
        ps += p;
      }
      for (int off = 1; off < 16; off <<= 1) ps += __shfl_xor(ps, off);
      lrow[r] = lrow[r] * al[r] + ps;
      mrow[r] = mn;
    }
    for (int nt2 = 0; nt2 < 16; ++nt2)
      for (int r = 0; r < 4; ++r) O[nt2][r] *= al[r];
    __asm__ volatile("s_waitcnt lgkmcnt(0)" ::: "memory");
    // PV: A = P[16x64] (A-layout from LDS), B-fragments from vT rows
    for (int ks = 0; ks < 2; ++ks) {
      const bf16x8 pf = *(const bf16x8*)&P[wid][l15][ks * 32 + quad * 8];
      for (int nt2 = 0; nt2 < 16; ++nt2) {
        const bf16x8 vf = *(const bf16x8*)(Vh + (size_t)(nt2 * 16 + l15) * S + kt + ks * 32 + quad * 8);
        O[nt2] = __builtin_amdgcn_mfma_f32_16x16x32_bf16(pf, vf, O[nt2], 0, 0, 0);
      }
    }
    __asm__ volatile("" ::: "memory");
  }
  for (int nt2 = 0; nt2 < 16; ++nt2)
    for (int r = 0; r < 4; ++r) {
      const float o = O[nt2][r] / lrow[r];
      Aout[(size_t)(q0 + wid * 16 + quad * 4 + r) * 2048 + h * 256 + nt2 * 16 + l15] = (__bf16)o;
    }
}

// ---------------------------------------------------------------------------
// O projection: out_f32[4096 x 2048] = attn_bf16 @ ow_f32^T (ow cast inline).
// grid (16, 32), block 256. [validated round 5]
// ---------------------------------------------------------------------------
__global__ __launch_bounds__(256, 2) void gemm_out(
    const __bf16* __restrict__ A, const float* __restrict__ B,
    float* __restrict__ C) {
  const int K = 2048, ldc = 2048;
  __shared__ __align__(16) __bf16 As[128 * 32];
  __shared__ __align__(16) __bf16 Bs[128 * 32];
  const int m0 = blockIdx.y * 128, n0 = blockIdx.x * 128;
  const int tid = threadIdx.x;
  const int wid = tid >> 6, lane = tid & 63, l15 = lane & 15, quad = lane >> 4;
  const int wm = wid >> 1, wn = wid & 1;

  f32x4v acc[4][4] = {};

  for (int kb = 0; kb < K; kb += 32) {
    for (int cc = 0; cc < 2; ++cc) {            // A: 512 bf16x8 chunks
      const int c = cc * 256 + tid;
      const int row = c >> 2, col = (c & 3) * 8;
      *(bf16x8*)&As[row * 32 + col] =
          *(const bf16x8*)(A + (size_t)(m0 + row) * K + kb + col);
    }
    for (int cc = 0; cc < 4; ++cc) {            // B: 1024 float4 chunks -> bf16
      const int c = cc * 256 + tid;
      const int row = c >> 3, col = (c & 7) * 4;
      const float4 bv = *(const float4*)(B + (size_t)(n0 + row) * K + kb + col);
      bf16x4 bh = {(__bf16)bv.x, (__bf16)bv.y, (__bf16)bv.z, (__bf16)bv.w};
      *(bf16x4*)&Bs[row * 32 + col] = bh;
    }
    __syncthreads();
    bf16x8 af[4], bfr[4];
    for (int mt = 0; mt < 4; ++mt)
      af[mt] = *(const bf16x8*)&As[(wm * 64 + mt * 16 + l15) * 32 + quad * 8];
    for (int nt = 0; nt < 4; ++nt)
      bfr[nt] = *(const bf16x8*)&Bs[(wn * 64 + nt * 16 + l15) * 32 + quad * 8];
    for (int mt = 0; mt < 4; ++mt)
      for (int nt = 0; nt < 4; ++nt)
        acc[mt][nt] = __builtin_amdgcn_mfma_f32_16x16x32_bf16(af[mt], bfr[nt], acc[mt][nt], 0, 0, 0);
    __syncthreads();
  }
  for (int mt = 0; mt < 4; ++mt)
    for (int nt = 0; nt < 4; ++nt) {
      const int row = m0 + wm * 64 + mt * 16 + quad * 4;
      const int col = n0 + wn * 64 + nt * 16 + l15;
      for (int r = 0; r < 4; ++r)
        C[(size_t)(row + r) * ldc + col] = acc[mt][nt][r];
    }
}

// ---------------------------------------------------------------------------
extern "C" void kernel_launch(void* const* d_in, const int* in_sizes, int n_in,
                              void* d_out, int out_size, void* d_ws, size_t ws_size,
                              hipStream_t stream) {
  const float* hidden = (const float*)d_in[0];
  const float* cosb   = (const float*)d_in[1];
  const float* sinb   = (const float*)d_in[2];
  const float* qw     = (const float*)d_in[3];
  const float* kw     = (const float*)d_in[4];
  const float* vw     = (const float*)d_in[5];
  const float* ow     = (const float*)d_in[6];
  const float* qnw    = (const float*)d_in[7];
  const float* knw    = (const float*)d_in[8];
  float* out = (float*)d_out;   // reference output dtype = float32

  // Workspace (128 MiB peak), lifetime-overlapped:
  //  [0,64)Mi   qkvf (f32) -> dead after norm_rope -> attn bf16 [0,16)
  //  [64,80)Mi  qh   [80,96)Mi ql   [96,104)Mi kh   [104,112)Mi kl
  //  [112,120)Mi vT ([4][256][4096] bf16)
  const size_t MB = 1048576;
  char* ws = (char*)d_ws;
  float*  qkvf = (float*)ws;
  __bf16* attn = (__bf16*)ws;
  __bf16* qh   = (__bf16*)(ws + 64 * MB);
  __bf16* ql   = (__bf16*)(ws + 80 * MB);
  __bf16* kh   = (__bf16*)(ws + 96 * MB);
  __bf16* kl   = (__bf16*)(ws + 104 * MB);
  __bf16* vT   = (__bf16*)(ws + 112 * MB);

  // 1) QKV projection (split-precision MFMA, f32 out)
  gemm_qkv<<<dim3(32, 32), 256, 0, stream>>>(hidden, qw, kw, vw, qkvf);
  // 2) f32 RMSNorm + RoPE; q/k hi-lo planes, v bf16 transposed
  norm_rope<<<dim3(4096, 16), 64, 0, stream>>>(qkvf, cosb, sinb, qnw, knw,
                                               qh, ql, kh, kl, vT);
  // 3) MFMA sliding-window flash attention (split QK^T)
  attn_mfma<<<dim3(64, 8), 256, 0, stream>>>(qh, ql, kh, kl, vT, attn);
  // 4) O projection -> f32 output
  gemm_out<<<dim3(16, 32), 256, 0, stream>>>(attn, ow, out);
}

// Round 7
// 820.927 us; speedup vs baseline: 2.3421x; 1.3004x over previous
//
#include <hip/hip_runtime.h>
#include <stdint.h>

typedef __bf16 bf16x8 __attribute__((ext_vector_type(8)));
typedef __bf16 bf16x4 __attribute__((ext_vector_type(4)));
typedef float f32x4v __attribute__((ext_vector_type(4)));

__device__ __forceinline__ void async_copy16(const void* gptr, void* ldsptr) {
  // wave-uniform LDS base; HW scatters lane i to base + i*16
  __builtin_amdgcn_global_load_lds(
      (const __attribute__((address_space(1))) void*)gptr,
      (__attribute__((address_space(3))) void*)ldsptr,
      16, 0, 0);
}

// ---------------------------------------------------------------------------
// f32 -> (hi, lo) bf16 split: hi = bf16(x), lo = bf16(x - hi). rep err ~2^-17.
// ---------------------------------------------------------------------------
__global__ __launch_bounds__(256) void cvt_split(
    const float* __restrict__ src, __bf16* __restrict__ hi,
    __bf16* __restrict__ lo, int n4) {
  const int i = blockIdx.x * 256 + threadIdx.x;
  if (i < n4) {
    const float4 v = ((const float4*)src)[i];
    float vv[4] = {v.x, v.y, v.z, v.w};
    bf16x4 h, l;
    for (int j = 0; j < 4; ++j) {
      h[j] = (__bf16)vv[j];
      l[j] = (__bf16)(vv[j] - (float)h[j]);
    }
    ((bf16x4*)hi)[i] = h;
    ((bf16x4*)lo)[i] = l;
  }
}

// ---------------------------------------------------------------------------
// QKV projection, m97 staging: C_f32 = (Ah+Al) @ (Bh+Bl)^T, 3-term split MFMA.
// global_load_lds width=16 on 4 bf16 planes; 48 MFMA per wave per k-block.
// grid (32, 32), block 256 (4 waves, 2x2 wave grid, 4x4 16x16x32 MFMA).
// ---------------------------------------------------------------------------
__global__ __launch_bounds__(256, 2) void gemm_qkv(
    const __bf16* __restrict__ Ah, const __bf16* __restrict__ Al,
    const __bf16* __restrict__ Bh, const __bf16* __restrict__ Bl,
    float* __restrict__ C) {
  const int K = 2048, ldc = 4096;
  __shared__ __align__(16) __bf16 Ash[128 * 32];
  __shared__ __align__(16) __bf16 Asl[128 * 32];
  __shared__ __align__(16) __bf16 Bsh[128 * 32];
  __shared__ __align__(16) __bf16 Bsl[128 * 32];
  const int m0 = blockIdx.y * 128, n0 = blockIdx.x * 128;
  const int tid = threadIdx.x;
  const int wid = tid >> 6, lane = tid & 63, l15 = lane & 15, quad = lane >> 4;
  const int wm = wid >> 1, wn = wid & 1;

  f32x4v acc[4][4] = {};

  for (int kb = 0; kb < K; kb += 32) {
    // 512 16B-chunks per plane; chunk c -> row c>>2, col (c&3)*8 (contiguous)
    for (int it = 0; it < 2; ++it) {
      const int c = (wid * 2 + it) * 64 + lane;
      const int row = c >> 2, col = (c & 3) * 8;
      const size_t ao = (size_t)(m0 + row) * K + kb + col;
      const size_t bo = (size_t)(n0 + row) * K + kb + col;
      const int dst = (wid * 2 + it) * 512;
      async_copy16(Ah + ao, &Ash[dst]);
      async_copy16(Al + ao, &Asl[dst]);
      async_copy16(Bh + bo, &Bsh[dst]);
      async_copy16(Bl + bo, &Bsl[dst]);
    }
    __syncthreads();  // drains vmcnt -> LDS tiles complete
    bf16x8 afh[4], afl[4], bfh[4], bfl[4];
    for (int mt = 0; mt < 4; ++mt) {
      const int o = (wm * 64 + mt * 16 + l15) * 32 + quad * 8;
      afh[mt] = *(const bf16x8*)&Ash[o];
      afl[mt] = *(const bf16x8*)&Asl[o];
    }
    for (int nt = 0; nt < 4; ++nt) {
      const int o = (wn * 64 + nt * 16 + l15) * 32 + quad * 8;
      bfh[nt] = *(const bf16x8*)&Bsh[o];
      bfl[nt] = *(const bf16x8*)&Bsl[o];
    }
    for (int mt = 0; mt < 4; ++mt)
      for (int nt = 0; nt < 4; ++nt) {
        acc[mt][nt] = __builtin_amdgcn_mfma_f32_16x16x32_bf16(afh[mt], bfh[nt], acc[mt][nt], 0, 0, 0);
        acc[mt][nt] = __builtin_amdgcn_mfma_f32_16x16x32_bf16(afh[mt], bfl[nt], acc[mt][nt], 0, 0, 0);
        acc[mt][nt] = __builtin_amdgcn_mfma_f32_16x16x32_bf16(afl[mt], bfh[nt], acc[mt][nt], 0, 0, 0);
      }
    __syncthreads();
  }
  // C/D layout: col = lane&15, row = quad*4 + reg
  for (int mt = 0; mt < 4; ++mt)
    for (int nt = 0; nt < 4; ++nt) {
      const int row = m0 + wm * 64 + mt * 16 + quad * 4;
      const int col = n0 + wn * 64 + nt * 16 + l15;
      for (int r = 0; r < 4; ++r)
        C[(size_t)(row + r) * ldc + col] = acc[mt][nt][r];
    }
}

// ---------------------------------------------------------------------------
// RMSNorm + RoPE, f32 internal. grid (4096, 16), block 64 (one wave).
// chunk 0..7 -> q head (hi/lo planes), 8..11 -> k head (hi/lo planes),
// 12..15 -> v head (norm only, bf16, TRANSPOSED [kvh][256][S] for PV).
// [validated round 6]
// ---------------------------------------------------------------------------
__global__ __launch_bounds__(64) void norm_rope(
    const float* __restrict__ qkv, const float* __restrict__ cosb,
    const float* __restrict__ sinb, const float* __restrict__ qnw,
    const float* __restrict__ knw,
    __bf16* __restrict__ qh, __bf16* __restrict__ ql,
    __bf16* __restrict__ kh, __bf16* __restrict__ kl,
    __bf16* __restrict__ vT) {
  const int s = blockIdx.x, c = blockIdx.y, lane = threadIdx.x;
  const int d0 = lane * 4;
  const float4 xv = *(const float4*)(qkv + (size_t)s * 4096 + c * 256 + d0);
  float v[4] = {xv.x, xv.y, xv.z, xv.w};
  float ss = v[0] * v[0] + v[1] * v[1] + v[2] * v[2] + v[3] * v[3];
  for (int off = 1; off < 64; off <<= 1) ss += __shfl_xor(ss, off);
  const float rn = rsqrtf(ss * (1.0f / 256.0f) + 1e-6f);
  if (c < 12) {
    const float* w = (c < 8) ? qnw : knw;
    float y[4], yp[4];
    for (int j = 0; j < 4; ++j) y[j] = v[j] * rn * w[d0 + j];
    for (int j = 0; j < 4; ++j) yp[j] = __shfl_xor(y[j], 32);  // d partner +/-128
    for (int j = 0; j < 4; ++j) {
      const int d = d0 + j;
      const float rot = (d < 128) ? -yp[j] : yp[j];
      y[j] = y[j] * cosb[s * 256 + d] + rot * sinb[s * 256 + d];
    }
    const size_t o = (c < 8) ? ((size_t)c * 4096 + s) * 256 + d0
                             : ((size_t)(c - 8) * 4096 + s) * 256 + d0;
    __bf16* dh = (c < 8) ? qh : kh;
    __bf16* dl = (c < 8) ? ql : kl;
    bf16x4 hv, lv;
    for (int j = 0; j < 4; ++j) {
      hv[j] = (__bf16)y[j];
      lv[j] = (__bf16)(y[j] - (float)hv[j]);
    }
    *(bf16x4*)(dh + o) = hv;
    *(bf16x4*)(dl + o) = lv;
  } else {
    const int kvh = c - 12;
    for (int j = 0; j < 4; ++j)
      vT[(size_t)(kvh * 256 + d0 + j) * 4096 + s] = (__bf16)(v[j] * rn);
  }
}

// ---------------------------------------------------------------------------
// MFMA flash attention, sliding window 1024, causal, NO softmax scale.
// QK^T split-precision (hi*hi + hi*lo + lo*hi); PV bf16.
// grid (S/64, H=8), block 256. GQA kv head = h>>1. [validated round 6]
// ---------------------------------------------------------------------------
__global__ __launch_bounds__(256, 2) void attn_mfma(
    const __bf16* __restrict__ Qh_, const __bf16* __restrict__ Ql_,
    const __bf16* __restrict__ Kh_, const __bf16* __restrict__ Kl_,
    const __bf16* __restrict__ VT, __bf16* __restrict__ Aout) {
  const int S = 4096, D = 256;
  const int h = blockIdx.y;
  const int q0 = blockIdx.x * 64;
  const int tid = threadIdx.x;
  const int wid = tid >> 6, lane = tid & 63, l15 = lane & 15, quad = lane >> 4;
  const int kv = h >> 1;
  __shared__ __align__(16) __bf16 P[4][16][64];  // per-wave P C->A round-trip

  const __bf16* Khh = Kh_ + (size_t)kv * S * D;
  const __bf16* Khl = Kl_ + (size_t)kv * S * D;
  const __bf16* Vh  = VT + (size_t)kv * D * S;

  // Q fragments hi/lo (A-layout: m=lane&15, k=quad*8+j)
  bf16x8 qfh[8], qfl[8];
  {
    const size_t qoff = (size_t)h * S * D + (size_t)(q0 + wid * 16 + l15) * D + quad * 8;
    for (int ks = 0; ks < 8; ++ks) {
      qfh[ks] = *(const bf16x8*)(Qh_ + qoff + ks * 32);
      qfl[ks] = *(const bf16x8*)(Ql_ + qoff + ks * 32);
    }
  }

  f32x4v O[16] = {};
  float mrow[4] = {-1e30f, -1e30f, -1e30f, -1e30f};
  float lrow[4] = {0.f, 0.f, 0.f, 0.f};

  const int lo = (q0 >= 1024) ? (q0 - 1024) : 0;
  for (int kt = lo; kt <= q0; kt += 64) {
    // scores [16 q x 64 keys]: 4 n-tiles x 8 k-steps x 3 split terms
    f32x4v sa[4] = {};
    for (int nt = 0; nt < 4; ++nt) {
      const size_t ko = (size_t)(kt + nt * 16 + l15) * D + quad * 8;
      for (int ks = 0; ks < 8; ++ks) {
        const bf16x8 kh8 = *(const bf16x8*)(Khh + ko + ks * 32);
        const bf16x8 kl8 = *(const bf16x8*)(Khl + ko + ks * 32);
        sa[nt] = __builtin_amdgcn_mfma_f32_16x16x32_bf16(qfh[ks], kh8, sa[nt], 0, 0, 0);
        sa[nt] = __builtin_amdgcn_mfma_f32_16x16x32_bf16(qfh[ks], kl8, sa[nt], 0, 0, 0);
        sa[nt] = __builtin_amdgcn_mfma_f32_16x16x32_bf16(qfl[ks], kh8, sa[nt], 0, 0, 0);
      }
    }
    // online softmax (C-layout: row = quad*4+r, col = l15 within n-tile)
    float al[4];
    for (int r = 0; r < 4; ++r) {
      const int i = q0 + wid * 16 + quad * 4 + r;
      float mx = -1e30f;
      for (int nt = 0; nt < 4; ++nt) {
        const int j = kt + nt * 16 + l15;
        const float svv = ((j <= i) && (i - j < 1024)) ? sa[nt][r] : -1e30f;
        sa[nt][r] = svv;
        mx = fmaxf(mx, svv);
      }
      for (int off = 1; off < 16; off <<= 1) mx = fmaxf(mx, __shfl_xor(mx, off));
      const float mn = fmaxf(mrow[r], mx);
      al[r] = __expf(mrow[r] - mn);
      float ps = 0.f;
      for (int nt = 0; nt < 4; ++nt) {
        // explicit zero for fully-masked history (else exp(0)=1 garbage)
        const float p = (mn <= -1e29f) ? 0.f : __expf(sa[nt][r] - mn);
        P[wid][quad * 4 + r][nt * 16 + l15] = (__bf16)p;
        ps += p;
      }
      for (int off = 1; off < 16; off <<= 1) ps += __shfl_xor(ps, off);
      lrow[r] = lrow[r] * al[r] + ps;
      mrow[r] = mn;
    }
    for (int nt2 = 0; nt2 < 16; ++nt2)
      for (int r = 0; r < 4; ++r) O[nt2][r] *= al[r];
    __asm__ volatile("s_waitcnt lgkmcnt(0)" ::: "memory");
    // PV: A = P[16x64] (A-layout from LDS), B-fragments from vT rows
    for (int ks = 0; ks < 2; ++ks) {
      const bf16x8 pf = *(const bf16x8*)&P[wid][l15][ks * 32 + quad * 8];
      for (int nt2 = 0; nt2 < 16; ++nt2) {
        const bf16x8 vf = *(const bf16x8*)(Vh + (size_t)(nt2 * 16 + l15) * S + kt + ks * 32 + quad * 8);
        O[nt2] = __builtin_amdgcn_mfma_f32_16x16x32_bf16(pf, vf, O[nt2], 0, 0, 0);
      }
    }
    __asm__ volatile("" ::: "memory");
  }
  for (int nt2 = 0; nt2 < 16; ++nt2)
    for (int r = 0; r < 4; ++r) {
      const float o = O[nt2][r] / lrow[r];
      Aout[(size_t)(q0 + wid * 16 + quad * 4 + r) * 2048 + h * 256 + nt2 * 16 + l15] = (__bf16)o;
    }
}

// ---------------------------------------------------------------------------
// O projection: out_f32[4096 x 2048] = attn_bf16 @ ow_f32^T (ow cast inline).
// grid (16, 32), block 256. [validated round 5]
// ---------------------------------------------------------------------------
__global__ __launch_bounds__(256, 2) void gemm_out(
    const __bf16* __restrict__ A, const float* __restrict__ B,
    float* __restrict__ C) {
  const int K = 2048, ldc = 2048;
  __shared__ __align__(16) __bf16 As[128 * 32];
  __shared__ __align__(16) __bf16 Bs[128 * 32];
  const int m0 = blockIdx.y * 128, n0 = blockIdx.x * 128;
  const int tid = threadIdx.x;
  const int wid = tid >> 6, lane = tid & 63, l15 = lane & 15, quad = lane >> 4;
  const int wm = wid >> 1, wn = wid & 1;

  f32x4v acc[4][4] = {};

  for (int kb = 0; kb < K; kb += 32) {
    for (int cc = 0; cc < 2; ++cc) {            // A: 512 bf16x8 chunks
      const int c = cc * 256 + tid;
      const int row = c >> 2, col = (c & 3) * 8;
      *(bf16x8*)&As[row * 32 + col] =
          *(const bf16x8*)(A + (size_t)(m0 + row) * K + kb + col);
    }
    for (int cc = 0; cc < 4; ++cc) {            // B: 1024 float4 chunks -> bf16
      const int c = cc * 256 + tid;
      const int row = c >> 3, col = (c & 7) * 4;
      const float4 bv = *(const float4*)(B + (size_t)(n0 + row) * K + kb + col);
      bf16x4 bh = {(__bf16)bv.x, (__bf16)bv.y, (__bf16)bv.z, (__bf16)bv.w};
      *(bf16x4*)&Bs[row * 32 + col] = bh;
    }
    __syncthreads();
    bf16x8 af[4], bfr[4];
    for (int mt = 0; mt < 4; ++mt)
      af[mt] = *(const bf16x8*)&As[(wm * 64 + mt * 16 + l15) * 32 + quad * 8];
    for (int nt = 0; nt < 4; ++nt)
      bfr[nt] = *(const bf16x8*)&Bs[(wn * 64 + nt * 16 + l15) * 32 + quad * 8];
    for (int mt = 0; mt < 4; ++mt)
      for (int nt = 0; nt < 4; ++nt)
        acc[mt][nt] = __builtin_amdgcn_mfma_f32_16x16x32_bf16(af[mt], bfr[nt], acc[mt][nt], 0, 0, 0);
    __syncthreads();
  }
  for (int mt = 0; mt < 4; ++mt)
    for (int nt = 0; nt < 4; ++nt) {
      const int row = m0 + wm * 64 + mt * 16 + quad * 4;
      const int col = n0 + wn * 64 + nt * 16 + l15;
      for (int r = 0; r < 4; ++r)
        C[(size_t)(row + r) * ldc + col] = acc[mt][nt][r];
    }
}

// ---------------------------------------------------------------------------
extern "C" void kernel_launch(void* const* d_in, const int* in_sizes, int n_in,
                              void* d_out, int out_size, void* d_ws, size_t ws_size,
                              hipStream_t stream) {
  const float* hidden = (const float*)d_in[0];
  const float* cosb   = (const float*)d_in[1];
  const float* sinb   = (const float*)d_in[2];
  const float* qw     = (const float*)d_in[3];
  const float* kw     = (const float*)d_in[4];
  const float* vw     = (const float*)d_in[5];
  const float* ow     = (const float*)d_in[6];
  const float* qnw    = (const float*)d_in[7];
  const float* knw    = (const float*)d_in[8];
  float* out = (float*)d_out;   // reference output dtype = float32

  // Workspace (128 MiB), lifetime-overlapped:
  //  [0,64)Mi   qkvf (f32) -> dead after norm_rope -> attn bf16 [0,16)
  //  [64,80)Mi  hh -> qh    [80,96)Mi  hl -> ql
  //  [96,112)Mi wh -> kh[96,104) kl[104,112)
  //  [112,128)Mi wl -> vT[112,120)
  const size_t MB = 1048576;
  char* ws = (char*)d_ws;
  float*  qkvf = (float*)ws;
  __bf16* attn = (__bf16*)ws;
  __bf16* hh   = (__bf16*)(ws + 64 * MB);
  __bf16* hl   = (__bf16*)(ws + 80 * MB);
  __bf16* wh   = (__bf16*)(ws + 96 * MB);
  __bf16* wl   = (__bf16*)(ws + 112 * MB);
  __bf16* qh   = (__bf16*)(ws + 64 * MB);
  __bf16* ql   = (__bf16*)(ws + 80 * MB);
  __bf16* kh   = (__bf16*)(ws + 96 * MB);
  __bf16* kl   = (__bf16*)(ws + 104 * MB);
  __bf16* vT   = (__bf16*)(ws + 112 * MB);

  // 0) f32 -> bf16 hi/lo split (hidden + packed [qw|kw|vw] weight planes)
  cvt_split<<<dim3(8192), 256, 0, stream>>>(hidden, hh, hl, 2097152);
  cvt_split<<<dim3(4096), 256, 0, stream>>>(qw, wh, wl, 1048576);
  cvt_split<<<dim3(2048), 256, 0, stream>>>(kw, wh + 4194304, wl + 4194304, 524288);
  cvt_split<<<dim3(2048), 256, 0, stream>>>(vw, wh + 6291456, wl + 6291456, 524288);

  // 1) QKV projection (split-precision MFMA, global_load_lds staging, f32 out)
  gemm_qkv<<<dim3(32, 32), 256, 0, stream>>>(hh, hl, wh, wl, qkvf);
  // 2) f32 RMSNorm + RoPE; q/k hi-lo planes, v bf16 transposed
  norm_rope<<<dim3(4096, 16), 64, 0, stream>>>(qkvf, cosb, sinb, qnw, knw,
                                               qh, ql, kh, kl, vT);
  // 3) MFMA sliding-window flash attention (split QK^T)
  attn_mfma<<<dim3(64, 8), 256, 0, stream>>>(qh, ql, kh, kl, vT, attn);
  // 4) O projection -> f32 output
  gemm_out<<<dim3(16, 32), 256, 0, stream>>>(attn, ow, out);
}